// Round 11
// baseline (155.866 us; speedup 1.0000x reference)
//
#include <hip/hip_runtime.h>

#define N_NODES 40000
#define IN_DIM 256
#define OUT_DIM 128
#define CAP 64                       // bucket capacity; P(deg>=64)~2e-18 for Poisson(16)
#define GEMM_BLOCKS 625              // N_NODES/64
#define FILL_BLOCKS 625              // E/(256*4)

typedef __bf16 bf16x8 __attribute__((ext_vector_type(8)));
typedef float floatx4 __attribute__((ext_vector_type(4)));

__device__ __forceinline__ int clamp_idx(int v) {
    unsigned u = (unsigned)v;
    return (u < (unsigned)N_NODES) ? v : 0;
}

// read edge element (low dword suffices: indices < 2^31, non-negative)
__device__ __forceinline__ int ld_edge(const int* e32, long long idx, int is64) {
    return is64 ? e32[2 * idx] : e32[idx];
}

__device__ __forceinline__ float bflo(unsigned u) {
    union { unsigned i; float f; } c; c.i = u << 16; return c.f;
}
__device__ __forceinline__ float bfhi(unsigned u) {
    union { unsigned i; float f; } c; c.i = u & 0xFFFF0000u; return c.f;
}

// ===== fused main (3-dispatch plan: memset(cnt) -> main -> gather) =====
// even blocks = MFMA gemm: convert raw W -> bf16 frag order directly into LDS
//   (2x32KB halves, replaces the prep kernel's wswz global round-trip)
// odd blocks  = edge fill: per-block dtype probe (odd dwords all zero <=> int64)
__global__ __launch_bounds__(256) void main_r23(
    const float* __restrict__ x, const float* __restrict__ W,
    __bf16* __restrict__ xwb,
    const void* __restrict__ edge, int E,
    int* __restrict__ cnt, unsigned short* __restrict__ bucket) {
    __shared__ __align__(16) float4 wlds4[2048];   // 32 KB: half of W in frag order
    int t = threadIdx.x;
    int bid = blockIdx.x;
    if ((bid & 1) == 0) {
        // ---- gemm: 4 waves, wave = 16 rows x 128 cols; W halves converted in LDS ----
        int gid = bid >> 1;                        // [0, 625)
        __bf16* wb = (__bf16*)wlds4;

        int wave = t >> 6, lane = t & 63;
        int quad = lane >> 4, m16 = lane & 15;
        int m = gid * 64 + wave * 16 + m16;
        const float* xrow = x + (long long)m * IN_DIM;
        const char* wl = (const char*)wlds4 + (lane << 4);   // frag offs are imm

        // conversion: thread covers W row k (within half), 64-col slice
        int krow = t >> 1;                         // 0..127 within half
        int c0 = (t & 1) * 64;

        floatx4 acc[8];
#pragma unroll
        for (int ct = 0; ct < 8; ++ct) acc[ct] = (floatx4){0.f, 0.f, 0.f, 0.f};

#pragma unroll
        for (int h = 0; h < 2; ++h) {
            if (h) __syncthreads();                // protect LDS reuse between halves
            // convert half h: W rows [h*128, h*128+128) -> frag-order LDS
            int k = h * 128 + krow;
            int jj = k & 7;
            int laneHi16 = ((k >> 3) & 3) * 16;
            int tbase = ((k >> 5) - h * 4) * 8;    // (kcg - h*4) * 8
            const float4* wrow4 = (const float4*)(W + (long long)k * OUT_DIM + c0);
#pragma unroll
            for (int f = 0; f < 16; ++f) {
                float4 w4 = wrow4[f];
                int n0 = c0 + 4 * f;
#pragma unroll
                for (int e = 0; e < 4; ++e) {
                    int n = n0 + e;
                    int idx = (tbase + (n >> 4)) * 512 + (laneHi16 + (n & 15)) * 8 + jj;
                    float v = (e == 0) ? w4.x : (e == 1) ? w4.y : (e == 2) ? w4.z : w4.w;
                    wb[idx] = (__bf16)v;
                }
            }
            __syncthreads();
            // MFMA over this half's 4 kc steps
#pragma unroll
            for (int kcl = 0; kcl < 4; ++kcl) {
                int kc = h * 4 + kcl;
                int k0 = kc * 32 + quad * 8;
                float4 xa = *(const float4*)(xrow + k0);
                float4 xb = *(const float4*)(xrow + k0 + 4);
                bf16x8 af;
                af[0] = (__bf16)xa.x; af[1] = (__bf16)xa.y;
                af[2] = (__bf16)xa.z; af[3] = (__bf16)xa.w;
                af[4] = (__bf16)xb.x; af[5] = (__bf16)xb.y;
                af[6] = (__bf16)xb.z; af[7] = (__bf16)xb.w;
#pragma unroll
                for (int ct = 0; ct < 8; ++ct) {
                    bf16x8 bf = *(const bf16x8*)(wl + ((kcl * 8 + ct) << 10));
                    acc[ct] = __builtin_amdgcn_mfma_f32_16x16x32_bf16(af, bf, acc[ct], 0, 0, 0);
                }
            }
        }

        // packed stores: dword slot p*16+m16 holds cols (p*32+m16, p*32+16+m16)
        unsigned* xwu = (unsigned*)xwb;
        int rbase = gid * 64 + wave * 16 + quad * 4;
#pragma unroll
        for (int p = 0; p < 4; ++p) {
#pragma unroll
            for (int r = 0; r < 4; ++r) {
                __bf16 lo = (__bf16)acc[2 * p][r];
                __bf16 hi = (__bf16)acc[2 * p + 1][r];
                unsigned u = ((unsigned)__builtin_bit_cast(unsigned short, hi) << 16)
                           | (unsigned)__builtin_bit_cast(unsigned short, lo);
                xwu[(long long)(rbase + r) * 64 + p * 16 + m16] = u;
            }
        }
    } else {
        // ---- fill: per-block dtype probe, then 4 edges/thread atomic chains ----
        const int* e32 = (const int*)edge;
        int* sh = (int*)wlds4;
        if (t == 0) sh[0] = 0;
        __syncthreads();
        int nz = 0;
#pragma unroll
        for (int q = 0; q < 4; ++q) nz |= e32[2 * (t * 4 + q) + 1];
        if (nz) sh[0] = 1;                         // benign race: all write 1
        __syncthreads();
        int is64 = !sh[0];                         // odd dwords all zero => int64

        long long base = (long long)(bid >> 1) * 1024 + t * 4;
        int s0 = clamp_idx(ld_edge(e32, base + 0, is64));
        int s1 = clamp_idx(ld_edge(e32, base + 1, is64));
        int s2 = clamp_idx(ld_edge(e32, base + 2, is64));
        int s3 = clamp_idx(ld_edge(e32, base + 3, is64));
        int d0 = clamp_idx(ld_edge(e32, E + base + 0, is64));
        int d1 = clamp_idx(ld_edge(e32, E + base + 1, is64));
        int d2 = clamp_idx(ld_edge(e32, E + base + 2, is64));
        int d3 = clamp_idx(ld_edge(e32, E + base + 3, is64));
        int p0 = atomicAdd(&cnt[d0], 1);
        int p1 = atomicAdd(&cnt[d1], 1);
        int p2 = atomicAdd(&cnt[d2], 1);
        int p3 = atomicAdd(&cnt[d3], 1);
        if (p0 < CAP) bucket[d0 * CAP + p0] = (unsigned short)s0;
        if (p1 < CAP) bucket[d1 * CAP + p1] = (unsigned short)s1;
        if (p2 < CAP) bucket[d2 * CAP + p2] = (unsigned short)s2;
        if (p3 < CAP) bucket[d3 * CAP + p3] = (unsigned short)s3;
    }
}

// ===== gather: one wave/node; ushort bucket; packed xwb layout (c, c+16) =====
__global__ void gather_r23(const unsigned short* __restrict__ bucket,
                           const int* __restrict__ cnt,
                           const unsigned* __restrict__ xwd, const float* __restrict__ b,
                           float* __restrict__ out) {
    int node = blockIdx.x * 4 + (threadIdx.x >> 6);
    int lane = threadIdx.x & 63;
    if (node >= N_NODES) return;
    int cc = (lane >> 4) * 32 + (lane & 15);     // low col; high col = cc+16
    float b0 = b[cc], b1 = b[cc + 16];
    int cn_true = cnt[node];
    int take = cn_true < CAP ? cn_true : CAP;
    float dd = rsqrtf((float)(cn_true + 1));     // +1 self-loop
    unsigned us = xwd[node * 64 + lane];
    float a0 = dd * dd * bflo(us);
    float a1 = dd * dd * bfhi(us);

    int s_l = 0; float nrm_l = 0.0f;
    if (lane < take) {
        s_l = (int)bucket[node * CAP + lane];    // one coalesced 2B/lane load
        nrm_l = dd * rsqrtf((float)(cnt[s_l] + 1));
    }
    int j = 0;
    for (; j + 8 <= take; j += 8) {
        int   s0 = __shfl(s_l, j),     s1 = __shfl(s_l, j + 1);
        int   s2 = __shfl(s_l, j + 2), s3 = __shfl(s_l, j + 3);
        int   s4 = __shfl(s_l, j + 4), s5 = __shfl(s_l, j + 5);
        int   s6 = __shfl(s_l, j + 6), s7 = __shfl(s_l, j + 7);
        float n0 = __shfl(nrm_l, j),     n1 = __shfl(nrm_l, j + 1);
        float n2 = __shfl(nrm_l, j + 2), n3 = __shfl(nrm_l, j + 3);
        float n4 = __shfl(nrm_l, j + 4), n5 = __shfl(nrm_l, j + 5);
        float n6 = __shfl(nrm_l, j + 6), n7 = __shfl(nrm_l, j + 7);
        unsigned u0 = xwd[s0 * 64 + lane], u1 = xwd[s1 * 64 + lane];
        unsigned u2 = xwd[s2 * 64 + lane], u3 = xwd[s3 * 64 + lane];
        unsigned u4 = xwd[s4 * 64 + lane], u5 = xwd[s5 * 64 + lane];
        unsigned u6 = xwd[s6 * 64 + lane], u7 = xwd[s7 * 64 + lane];
        a0 += n0 * bflo(u0); a1 += n0 * bfhi(u0);
        a0 += n1 * bflo(u1); a1 += n1 * bfhi(u1);
        a0 += n2 * bflo(u2); a1 += n2 * bfhi(u2);
        a0 += n3 * bflo(u3); a1 += n3 * bfhi(u3);
        a0 += n4 * bflo(u4); a1 += n4 * bfhi(u4);
        a0 += n5 * bflo(u5); a1 += n5 * bfhi(u5);
        a0 += n6 * bflo(u6); a1 += n6 * bfhi(u6);
        a0 += n7 * bflo(u7); a1 += n7 * bfhi(u7);
    }
    for (; j < take; ++j) {
        int   s = __shfl(s_l, j);
        float n = __shfl(nrm_l, j);
        unsigned u = xwd[s * 64 + lane];
        a0 += n * bflo(u); a1 += n * bfhi(u);
    }
    out[(long long)node * OUT_DIM + cc]      = fmaxf(a0 + b0, 0.0f);
    out[(long long)node * OUT_DIM + cc + 16] = fmaxf(a1 + b1, 0.0f);
}

extern "C" void kernel_launch(void* const* d_in, const int* in_sizes, int n_in,
                              void* d_out, int out_size, void* d_ws, size_t ws_size,
                              hipStream_t stream) {
    const float* x   = (const float*)d_in[0];
    const void* edge = d_in[1];                 // int32 or int64, detected on device
    const float* W   = (const float*)d_in[2];
    const float* b   = (const float*)d_in[3];
    float* out       = (float*)d_out;           // fp32 output

    int E = in_sizes[1] / 2;                    // 640000

    char* ws = (char*)d_ws;
    // layout: cnt 160000 | bucket(u16) 5120000 | xwb 10240000
    int*            cnt    = (int*)(ws);
    unsigned short* bucket = (unsigned short*)(ws + 160000);
    __bf16*         xwb    = (__bf16*)(ws + 5280000);

    hipMemsetAsync(cnt, 0, N_NODES * sizeof(int), stream);
    main_r23<<<GEMM_BLOCKS + FILL_BLOCKS, 256, 0, stream>>>(
        x, W, xwb, edge, E, cnt, bucket);
    gather_r23<<<N_NODES / 4, 256, 0, stream>>>(bucket, cnt, (const unsigned*)xwb, b, out);
}

// Round 12
// 141.577 us; speedup vs baseline: 1.1009x; 1.1009x over previous
//
#include <hip/hip_runtime.h>

#define N_NODES 40000
#define IN_DIM 256
#define OUT_DIM 128
#define CAP 64                       // bucket capacity; P(deg>=64)~2e-18 for Poisson(16)
#define GEMM_BLOCKS 625              // N_NODES/64
#define FILL_BLOCKS 625              // E/(256*4)

typedef __bf16 bf16x8 __attribute__((ext_vector_type(8)));
typedef float floatx4 __attribute__((ext_vector_type(4)));

__device__ __forceinline__ int clamp_idx(int v) {
    unsigned u = (unsigned)v;
    return (u < (unsigned)N_NODES) ? v : 0;
}

// read edge element (low dword suffices: indices < 2^31, non-negative)
__device__ __forceinline__ int ld_edge(const int* e32, long long idx, int is64) {
    return is64 ? e32[2 * idx] : e32[idx];
}

__device__ __forceinline__ float bflo(unsigned u) {
    union { unsigned i; float f; } c; c.i = u << 16; return c.f;
}
__device__ __forceinline__ float bfhi(unsigned u) {
    union { unsigned i; float f; } c; c.i = u & 0xFFFF0000u; return c.f;
}

// ===== prep: zero cnt + wconv (W -> bf16 B-frag order) + dtype detect =====
__global__ void prep_r24(const int* __restrict__ edge32, int* __restrict__ flag,
                         int* __restrict__ cnt, const float* __restrict__ W,
                         __bf16* __restrict__ wswz) {
    int i = blockIdx.x * 256 + threadIdx.x;
    if (i < N_NODES) cnt[i] = 0;
    if (i < IN_DIM * OUT_DIM) {      // 32768 frag elems
        int j    = i & 7;
        int lane = (i >> 3) & 63;
        int tile = i >> 9;           // kc*8+ct
        int ct = tile & 7, kc = tile >> 3;
        int k = kc * 32 + (lane >> 4) * 8 + j;
        int n = ct * 16 + (lane & 15);
        wswz[i] = (__bf16)W[k * OUT_DIM + n];
    }
    if (blockIdx.x == 0) {
        __shared__ int sh[256];
        int t = threadIdx.x;
        int nz = 0;
        for (int k = t; k < 1000; k += 256) nz |= (edge32[2 * k + 1] != 0);
        sh[t] = nz;
        __syncthreads();
        for (int off = 128; off > 0; off >>= 1) {
            if (t < off) sh[t] |= sh[t + off];
            __syncthreads();
        }
        if (t == 0) *flag = sh[0] ? 0 : 1;   // 1 => int64
    }
}

// ===== fused main: even blocks = MFMA gemm (W staged in 2x32KB LDS halves);
//       odd = edge fill. 32KB LDS -> 5 blocks/CU. =====
__global__ __launch_bounds__(256) void main_r24(
    const float* __restrict__ x, const __bf16* __restrict__ wswz,
    __bf16* __restrict__ xwb,
    const void* __restrict__ edge, int E, const int* __restrict__ flag,
    int* __restrict__ cnt, unsigned short* __restrict__ bucket) {
    __shared__ __align__(16) float4 wlds4[2048];   // 32 KB: half of wswz
    int t = threadIdx.x;
    int bid = blockIdx.x;
    if ((bid & 1) == 0) {
        // ---- gemm: 4 waves, wave = 16 rows x 128 cols; W halves from LDS ----
        int gid = bid >> 1;                        // [0, 625)
        const float4* wsrc = (const float4*)wswz;

        int wave = t >> 6, lane = t & 63;
        int quad = lane >> 4, m16 = lane & 15;
        int m = gid * 64 + wave * 16 + m16;
        const float* xrow = x + (long long)m * IN_DIM;
        const char* wl = (const char*)wlds4 + (lane << 4);   // frag offs are imm

        floatx4 acc[8];
#pragma unroll
        for (int ct = 0; ct < 8; ++ct) acc[ct] = (floatx4){0.f, 0.f, 0.f, 0.f};

        // ---- half A: tiles 0-31 (kc 0-3) ----
#pragma unroll
        for (int i = 0; i < 8; ++i) wlds4[i * 256 + t] = wsrc[i * 256 + t];
        __syncthreads();
#pragma unroll
        for (int kc = 0; kc < 4; ++kc) {
            int k0 = kc * 32 + quad * 8;
            float4 xa = *(const float4*)(xrow + k0);
            float4 xb = *(const float4*)(xrow + k0 + 4);
            bf16x8 af;
            af[0] = (__bf16)xa.x; af[1] = (__bf16)xa.y;
            af[2] = (__bf16)xa.z; af[3] = (__bf16)xa.w;
            af[4] = (__bf16)xb.x; af[5] = (__bf16)xb.y;
            af[6] = (__bf16)xb.z; af[7] = (__bf16)xb.w;
#pragma unroll
            for (int ct = 0; ct < 8; ++ct) {
                bf16x8 bf = *(const bf16x8*)(wl + ((kc * 8 + ct) << 10));  // ds_read_b128
                acc[ct] = __builtin_amdgcn_mfma_f32_16x16x32_bf16(af, bf, acc[ct], 0, 0, 0);
            }
        }
        __syncthreads();

        // ---- half B: tiles 32-63 (kc 4-7) ----
#pragma unroll
        for (int i = 0; i < 8; ++i) wlds4[i * 256 + t] = wsrc[2048 + i * 256 + t];
        __syncthreads();
#pragma unroll
        for (int kc = 4; kc < 8; ++kc) {
            int k0 = kc * 32 + quad * 8;
            float4 xa = *(const float4*)(xrow + k0);
            float4 xb = *(const float4*)(xrow + k0 + 4);
            bf16x8 af;
            af[0] = (__bf16)xa.x; af[1] = (__bf16)xa.y;
            af[2] = (__bf16)xa.z; af[3] = (__bf16)xa.w;
            af[4] = (__bf16)xb.x; af[5] = (__bf16)xb.y;
            af[6] = (__bf16)xb.z; af[7] = (__bf16)xb.w;
#pragma unroll
            for (int ct = 0; ct < 8; ++ct) {
                bf16x8 bf = *(const bf16x8*)(wl + (((kc - 4) * 8 + ct) << 10));
                acc[ct] = __builtin_amdgcn_mfma_f32_16x16x32_bf16(af, bf, acc[ct], 0, 0, 0);
            }
        }

        // packed stores: dword slot p*16+m16 holds cols (p*32+m16, p*32+16+m16)
        unsigned* xwu = (unsigned*)xwb;
        int rbase = gid * 64 + wave * 16 + quad * 4;
#pragma unroll
        for (int p = 0; p < 4; ++p) {
#pragma unroll
            for (int r = 0; r < 4; ++r) {
                __bf16 lo = (__bf16)acc[2 * p][r];
                __bf16 hi = (__bf16)acc[2 * p + 1][r];
                unsigned u = ((unsigned)__builtin_bit_cast(unsigned short, hi) << 16)
                           | (unsigned)__builtin_bit_cast(unsigned short, lo);
                xwu[(long long)(rbase + r) * 64 + p * 16 + m16] = u;
            }
        }
    } else {
        // ---- fill: 4 edges/thread, independent atomic chains ----
        int is64 = *flag;
        const int* e32 = (const int*)edge;
        long long base = (long long)(bid >> 1) * 1024 + t * 4;
        int s0 = clamp_idx(ld_edge(e32, base + 0, is64));
        int s1 = clamp_idx(ld_edge(e32, base + 1, is64));
        int s2 = clamp_idx(ld_edge(e32, base + 2, is64));
        int s3 = clamp_idx(ld_edge(e32, base + 3, is64));
        int d0 = clamp_idx(ld_edge(e32, E + base + 0, is64));
        int d1 = clamp_idx(ld_edge(e32, E + base + 1, is64));
        int d2 = clamp_idx(ld_edge(e32, E + base + 2, is64));
        int d3 = clamp_idx(ld_edge(e32, E + base + 3, is64));
        int p0 = atomicAdd(&cnt[d0], 1);
        int p1 = atomicAdd(&cnt[d1], 1);
        int p2 = atomicAdd(&cnt[d2], 1);
        int p3 = atomicAdd(&cnt[d3], 1);
        if (p0 < CAP) bucket[d0 * CAP + p0] = (unsigned short)s0;
        if (p1 < CAP) bucket[d1 * CAP + p1] = (unsigned short)s1;
        if (p2 < CAP) bucket[d2 * CAP + p2] = (unsigned short)s2;
        if (p3 < CAP) bucket[d3 * CAP + p3] = (unsigned short)s3;
    }
}

// ===== gather: one wave/node; ushort bucket; packed xwb layout (c, c+16) =====
__global__ void gather_r24(const unsigned short* __restrict__ bucket,
                           const int* __restrict__ cnt,
                           const unsigned* __restrict__ xwd, const float* __restrict__ b,
                           float* __restrict__ out) {
    int node = blockIdx.x * 4 + (threadIdx.x >> 6);
    int lane = threadIdx.x & 63;
    if (node >= N_NODES) return;
    int cc = (lane >> 4) * 32 + (lane & 15);     // low col; high col = cc+16
    float b0 = b[cc], b1 = b[cc + 16];
    int cn_true = cnt[node];
    int take = cn_true < CAP ? cn_true : CAP;
    float dd = rsqrtf((float)(cn_true + 1));     // +1 self-loop
    unsigned us = xwd[node * 64 + lane];
    float a0 = dd * dd * bflo(us);
    float a1 = dd * dd * bfhi(us);

    int s_l = 0; float nrm_l = 0.0f;
    if (lane < take) {
        s_l = (int)bucket[node * CAP + lane];    // one coalesced 2B/lane load
        nrm_l = dd * rsqrtf((float)(cnt[s_l] + 1));
    }
    int j = 0;
    for (; j + 8 <= take; j += 8) {
        int   s0 = __shfl(s_l, j),     s1 = __shfl(s_l, j + 1);
        int   s2 = __shfl(s_l, j + 2), s3 = __shfl(s_l, j + 3);
        int   s4 = __shfl(s_l, j + 4), s5 = __shfl(s_l, j + 5);
        int   s6 = __shfl(s_l, j + 6), s7 = __shfl(s_l, j + 7);
        float n0 = __shfl(nrm_l, j),     n1 = __shfl(nrm_l, j + 1);
        float n2 = __shfl(nrm_l, j + 2), n3 = __shfl(nrm_l, j + 3);
        float n4 = __shfl(nrm_l, j + 4), n5 = __shfl(nrm_l, j + 5);
        float n6 = __shfl(nrm_l, j + 6), n7 = __shfl(nrm_l, j + 7);
        unsigned u0 = xwd[s0 * 64 + lane], u1 = xwd[s1 * 64 + lane];
        unsigned u2 = xwd[s2 * 64 + lane], u3 = xwd[s3 * 64 + lane];
        unsigned u4 = xwd[s4 * 64 + lane], u5 = xwd[s5 * 64 + lane];
        unsigned u6 = xwd[s6 * 64 + lane], u7 = xwd[s7 * 64 + lane];
        a0 += n0 * bflo(u0); a1 += n0 * bfhi(u0);
        a0 += n1 * bflo(u1); a1 += n1 * bfhi(u1);
        a0 += n2 * bflo(u2); a1 += n2 * bfhi(u2);
        a0 += n3 * bflo(u3); a1 += n3 * bfhi(u3);
        a0 += n4 * bflo(u4); a1 += n4 * bfhi(u4);
        a0 += n5 * bflo(u5); a1 += n5 * bfhi(u5);
        a0 += n6 * bflo(u6); a1 += n6 * bfhi(u6);
        a0 += n7 * bflo(u7); a1 += n7 * bfhi(u7);
    }
    for (; j < take; ++j) {
        int   s = __shfl(s_l, j);
        float n = __shfl(nrm_l, j);
        unsigned u = xwd[s * 64 + lane];
        a0 += n * bflo(u); a1 += n * bfhi(u);
    }
    out[(long long)node * OUT_DIM + cc]      = fmaxf(a0 + b0, 0.0f);
    out[(long long)node * OUT_DIM + cc + 16] = fmaxf(a1 + b1, 0.0f);
}

extern "C" void kernel_launch(void* const* d_in, const int* in_sizes, int n_in,
                              void* d_out, int out_size, void* d_ws, size_t ws_size,
                              hipStream_t stream) {
    const float* x   = (const float*)d_in[0];
    const void* edge = d_in[1];                 // int32 or int64, detected on device
    const float* W   = (const float*)d_in[2];
    const float* b   = (const float*)d_in[3];
    float* out       = (float*)d_out;           // fp32 output

    int E = in_sizes[1] / 2;                    // 640000

    char* ws = (char*)d_ws;
    // layout: cnt 160000 | flag 256 | wswz 65536 | bucket(u16) 5120000 | xwb 10240000
    int*            cnt    = (int*)(ws);
    int*            flag   = (int*)(ws + 160000);
    __bf16*         wswz   = (__bf16*)(ws + 160256);
    unsigned short* bucket = (unsigned short*)(ws + 225792);
    __bf16*         xwb    = (__bf16*)(ws + 5345792);

    prep_r24<<<160, 256, 0, stream>>>((const int*)edge, flag, cnt, W, wswz);
    main_r24<<<GEMM_BLOCKS + FILL_BLOCKS, 256, 0, stream>>>(
        x, wswz, xwb, edge, E, flag, cnt, bucket);
    gather_r24<<<N_NODES / 4, 256, 0, stream>>>(bucket, cnt, (const unsigned*)xwb, b, out);
}